// Round 15
// baseline (322.830 us; speedup 1.0000x reference)
//
#include <hip/hip_runtime.h>

// LSTM sliding-window scan, fully independent 16-step windows (measured:
// zero warm-up -> absmax == bf16 floor). Round-15: nt=2 windows/block (32
// GEMM columns) to fit the unified VGPR+AGPR budget under 128 regs ->
// 4 waves/SIMD = TWO phase-independent blocks per CU (round 14 showed 1
// block/CU: combined ~180 regs; all waves barrier-phase-locked -> 53% idle).
// Grid 960 = (120 window-pairs x 8 batch-groups). Gates via MFMA bf16
// 16x16x32: wave w owns units 16w..16w+15 (M-tiles {w,8+w,16+w,24+w}); lane
// holds gates i,f,g,o of units 16w+4lq+r for columns 16nt+lm -> c/h update
// fully in-lane. H in LDS in B-fragment order per nt-region. Activation
// scale -log2e (-2log2e for g) folded into bf16 weights; (wih,bias) packed
// bf16x2 (1 reg per (mt,r)); h pack via v_cvt_pk_bf16_f32 when present.

#define TT   256
#define WIN  16
#define L2E  1.4426950408889634f

typedef __bf16 bf8 __attribute__((ext_vector_type(8)));
typedef short  s8v __attribute__((ext_vector_type(8)));
typedef float  f4v __attribute__((ext_vector_type(4)));
typedef int    i2v __attribute__((ext_vector_type(2)));

__device__ __forceinline__ unsigned short f2bf(float f) {
    unsigned u = __builtin_bit_cast(unsigned, f);
    return (unsigned short)((u + 0x8000u) >> 16);   // round-half-up to bf16
}
__device__ __forceinline__ float bf2f(short h) {
    return __builtin_bit_cast(float, ((unsigned)(unsigned short)h) << 16);
}
__device__ __forceinline__ int pk_bf16(float a, float b) {
#if __has_builtin(__builtin_amdgcn_cvt_pk_bf16_f32)
    return __builtin_bit_cast(int, __builtin_amdgcn_cvt_pk_bf16_f32(a, b));
#else
    return (int)(unsigned)f2bf(a) | ((int)(unsigned)f2bf(b) << 16);
#endif
}
__device__ __forceinline__ float sig_e2(float g) {   // gate pre-scaled by -log2e
    return __builtin_amdgcn_rcpf(1.0f + __builtin_amdgcn_exp2f(g));
}

__global__ void __launch_bounds__(512, 4)   // min 4 waves/EU -> <=128 regs
lstm_mfma_kernel(const float* __restrict__ x,
                 const float* __restrict__ W_ih,
                 const float* __restrict__ W_hh,
                 const float* __restrict__ b_ih,
                 const float* __restrict__ b_hh,
                 const float* __restrict__ fc_W,
                 const float* __restrict__ fc_b,
                 float* __restrict__ out)
{
    const int pb = blockIdx.x;        // window pair 0..119
    const int g  = blockIdx.y;        // batch group 0..7
    const int j  = threadIdx.x;
    const int w  = j >> 6;            // wave 0..7
    const int l  = j & 63;
    const int lm = l & 15;            // m (A) / n (B,C) index within tile
    const int lq = l >> 4;            // quad 0..3

    const int w0 = 2 * pb;            // windows w0, w0+1 = nt 0,1
    const int base_b = 16 * g;

    // H layout (shorts): [buf][ nt*2048 + kt*512 + lq*128 + n*8 + jj ]
    __shared__ short Hbuf[2][4096];
    __shared__ float xst[16 * 32];    // [step][col]  col = nt*16 + n
    __shared__ float parts[256];

    // ---- A-fragments: wave w, M-tile mt -> rows mt*128 + 16w + lm,
    //      k = kt*32 + lq*8 + jj. Pre-scaled by Kc(mt). 64 VGPRs. ----
    bf8 afr[4][4];                    // [mt][kt]
    int wbpk[4][4];                   // [mt][r]: lo=Kc*W_ih bf16, hi=Kc*bias bf16
#pragma unroll
    for (int mt = 0; mt < 4; ++mt) {
        const float Kc = (mt == 2) ? (-2.0f * L2E) : (-L2E);
        const int row = mt * 128 + 16 * w + lm;
#pragma unroll
        for (int kt = 0; kt < 4; ++kt) {
            const float* src = W_hh + row * 128 + kt * 32 + lq * 8;
            float4 v0 = ((const float4*)src)[0];
            float4 v1 = ((const float4*)src)[1];
            s8v t;
            t[0]=(short)f2bf(Kc*v0.x); t[1]=(short)f2bf(Kc*v0.y);
            t[2]=(short)f2bf(Kc*v0.z); t[3]=(short)f2bf(Kc*v0.w);
            t[4]=(short)f2bf(Kc*v1.x); t[5]=(short)f2bf(Kc*v1.y);
            t[6]=(short)f2bf(Kc*v1.z); t[7]=(short)f2bf(Kc*v1.w);
            afr[mt][kt] = __builtin_bit_cast(bf8, t);
        }
#pragma unroll
        for (int r = 0; r < 4; ++r) {
            const int rr = mt * 128 + 16 * w + 4 * lq + r;
            wbpk[mt][r] = (int)(unsigned)f2bf(Kc * W_ih[rr]) |
                          ((int)(unsigned)f2bf(Kc * (b_ih[rr] + b_hh[rr])) << 16);
        }
    }

    // ---- stage x: col c = nt*16+n runs window w0+nt of batch base_b+n ----
    {   // 16 steps x 32 cols = 512 = one element per thread
        const int t = j >> 5, c = j & 31;
        const int nt = c >> 4, n = c & 15;
        xst[j] = x[(base_b + n) * TT + (w0 + nt) + t];
    }
    for (int i = j; i < 4096; i += 512) Hbuf[0][i] = 0;   // h(0) = 0

    if (pb == 0 && j < 256) {         // out[:, :16] = x[:, :16]
        const int n = j >> 4, tt = j & 15;
        out[(base_b + n) * TT + tt] = x[(base_b + n) * TT + tt];
    }

    // h-write address: lane owns units u0..u0+3 (consecutive jj, one b64/nt)
    const int u0   = 16 * w + 4 * lq;
    const int wofh = (u0 >> 5) * 512 + ((u0 >> 3) & 3) * 128 + lm * 8 + (u0 & 7);

    float cst[2][4] = {};             // [nt][r]
    __syncthreads();

    for (int t = 0; t < 16; ++t) {
        const short* hb = &Hbuf[t & 1][0];
        const float xt0 = xst[t * 32 + lm];
        const float xt1 = xst[t * 32 + 16 + lm];
        f4v cv[4][2];                 // [mt][nt]
#pragma unroll
        for (int mt = 0; mt < 4; ++mt)
#pragma unroll
            for (int r = 0; r < 4; ++r) {
                const int pk = wbpk[mt][r];
                const float wihf  = __builtin_bit_cast(float, pk << 16);
                const float biasf = __builtin_bit_cast(float, pk & 0xffff0000);
                cv[mt][0][r] = fmaf(xt0, wihf, biasf);
                cv[mt][1][r] = fmaf(xt1, wihf, biasf);
            }
#pragma unroll
        for (int kt = 0; kt < 4; ++kt) {
            bf8 bfr[2];
#pragma unroll
            for (int nt = 0; nt < 2; ++nt)   // b128 at lane*16 within region
                bfr[nt] = *(const bf8*)(hb + nt * 2048 + kt * 512 + l * 8);
#pragma unroll
            for (int nt = 0; nt < 2; ++nt)
#pragma unroll
                for (int mt = 0; mt < 4; ++mt)
                    cv[mt][nt] = __builtin_amdgcn_mfma_f32_16x16x32_bf16(
                                     afr[mt][kt], bfr[nt], cv[mt][nt], 0, 0, 0);
        }
        short* hw = &Hbuf[(t + 1) & 1][0] + wofh;
#pragma unroll
        for (int nt = 0; nt < 2; ++nt) {
            float hv4[4];
#pragma unroll
            for (int r = 0; r < 4; ++r) {
                const float ai = sig_e2(cv[0][nt][r]);
                const float af = sig_e2(cv[1][nt][r]);
                const float ag = fmaf(2.0f, sig_e2(cv[2][nt][r]), -1.0f);
                const float ao = sig_e2(cv[3][nt][r]);
                cst[nt][r] = fmaf(af, cst[nt][r], ai * ag);
                const float tc = fmaf(2.0f, sig_e2(-2.0f * L2E * cst[nt][r]), -1.0f);
                hv4[r] = ao * tc;
            }
            i2v pk;
            pk[0] = pk_bf16(hv4[0], hv4[1]);
            pk[1] = pk_bf16(hv4[2], hv4[3]);
            *(i2v*)(hw + nt * 2048) = pk;
        }
        __syncthreads();
    }

    // ---- epilogue: col c -> out[base_b+(c&15)][16 + w0 + (c>>4)] ----
    // h_final in Hbuf[0] (16 steps, even). 8 threads/col, 16 units each.
    if (j < 256) {
        const int c  = j >> 3;        // 0..31
        const int p  = j & 7;         // unit chunk: units p*16 .. p*16+15
        const int nt = c >> 4, n = c & 15;
        const short* hf = &Hbuf[0][0] + nt * 2048;
        float acc = 0.f;
#pragma unroll
        for (int h8 = 0; h8 < 2; ++h8) {
            const int ub = p * 16 + 8 * h8;        // ub&7 == 0
            const s8v hv = *(const s8v*)(hf + (ub >> 5) * 512 +
                                         ((ub >> 3) & 3) * 128 + n * 8);
#pragma unroll
            for (int ii = 0; ii < 8; ++ii)
                acc = fmaf(fc_W[ub + ii], bf2f(hv[ii]), acc);
        }
        parts[j] = acc;
    }
    __syncthreads();
    if (j < 32) {
        float v = fc_b[0];
#pragma unroll
        for (int k = 0; k < 8; ++k) v += parts[j * 8 + k];
        const int nt = j >> 4, n = j & 15;
        out[(base_b + n) * TT + WIN + w0 + nt] = (v >= 0.f) ? v : 0.3f * v;
    }
}

extern "C" void kernel_launch(void* const* d_in, const int* in_sizes, int n_in,
                              void* d_out, int out_size, void* d_ws, size_t ws_size,
                              hipStream_t stream) {
    const float* x    = (const float*)d_in[0];
    const float* W_ih = (const float*)d_in[1];
    const float* W_hh = (const float*)d_in[2];
    const float* b_ih = (const float*)d_in[3];
    const float* b_hh = (const float*)d_in[4];
    const float* fc_W = (const float*)d_in[5];
    const float* fc_b = (const float*)d_in[6];
    float* out = (float*)d_out;

    lstm_mfma_kernel<<<dim3(120, 8), dim3(512), 0, stream>>>(
        x, W_ih, W_hh, b_ih, b_hh, fc_W, fc_b, out);
}

// Round 16
// 194.908 us; speedup vs baseline: 1.6563x; 1.6563x over previous
//
#include <hip/hip_runtime.h>

// LSTM sliding-window scan, fully independent 16-step windows (measured:
// zero warm-up -> absmax == bf16 floor). Round-16: fp8-e4m3 A/B fragments
// (mfma_f32_16x16x32_fp8_fp8) to halve the A-fragment VGPRs (64->32) so the
// whole live set (~103 regs) fits 4 waves/SIMD -> TWO phase-independent
// blocks/CU (round 15 proved 2 blocks/CU is reachable but spilled at bf16).
// nt=2 windows/block (32 GEMM columns), grid 960 = (120 pairs x 8 groups).
// Wave w owns units 16w..16w+15 (M-tiles {w,8+w,16+w,24+w}); lane holds
// gates i,f,g,o of units 16w+4lq+r for cols 16nt+lm -> c/h update in-lane.
// H in LDS as fp8 in B-fragment order; final-step h ALSO stored bf16 for
// the fc epilogue (kills fp8 quantization of the output dot). Activation
// scale -log2e (-2log2e for g) folded into fp8 weights; (wih,bias) packed
// bf16x2; c fp32.

#define TT   256
#define WIN  16
#define L2E  1.4426950408889634f

typedef short  s8v __attribute__((ext_vector_type(8)));
typedef float  f4v __attribute__((ext_vector_type(4)));
typedef int    i2v __attribute__((ext_vector_type(2)));
typedef long long i64;

__device__ __forceinline__ unsigned short f2bf(float f) {
    unsigned u = __builtin_bit_cast(unsigned, f);
    return (unsigned short)((u + 0x8000u) >> 16);   // round-half-up to bf16
}
__device__ __forceinline__ float bf2f(short h) {
    return __builtin_bit_cast(float, ((unsigned)(unsigned short)h) << 16);
}
__device__ __forceinline__ int pk_bf16(float a, float b) {
#if __has_builtin(__builtin_amdgcn_cvt_pk_bf16_f32)
    return __builtin_bit_cast(int, __builtin_amdgcn_cvt_pk_bf16_f32(a, b));
#else
    return (int)(unsigned)f2bf(a) | ((int)(unsigned)f2bf(b) << 16);
#endif
}
__device__ __forceinline__ float sig_e2(float g) {   // gate pre-scaled by -log2e
    return __builtin_amdgcn_rcpf(1.0f + __builtin_amdgcn_exp2f(g));
}

__global__ void __launch_bounds__(512, 4)   // 4 waves/EU -> <=128 regs, 2 blocks/CU
lstm_mfma_kernel(const float* __restrict__ x,
                 const float* __restrict__ W_ih,
                 const float* __restrict__ W_hh,
                 const float* __restrict__ b_ih,
                 const float* __restrict__ b_hh,
                 const float* __restrict__ fc_W,
                 const float* __restrict__ fc_b,
                 float* __restrict__ out)
{
    const int pb = blockIdx.x;        // window pair 0..119
    const int g  = blockIdx.y;        // batch group 0..7
    const int j  = threadIdx.x;
    const int w  = j >> 6;            // wave 0..7
    const int l  = j & 63;
    const int lm = l & 15;            // m (A) / n (B,C) index within tile
    const int lq = l >> 4;            // quad 0..3

    const int w0 = 2 * pb;            // windows w0, w0+1 = nt 0,1
    const int base_b = 16 * g;

    // H layout (fp8 bytes): [buf][ nt*2048 + kt*512 + lq*128 + n*8 + jj ]
    __shared__ char  Hbuf[2][4096];
    __shared__ short hfin[4096];      // bf16 final h: [nt*2048 + n*128 + u]
    __shared__ float xst[16 * 32];    // [step][col]  col = nt*16 + n
    __shared__ float parts[256];

    // ---- A-fragments: wave w, M-tile mt -> rows mt*128 + 16w + lm,
    //      k = kt*32 + lq*8 + jj. Pre-scaled by Kc(mt), fp8 e4m3. 32 VGPRs. ----
    i64 afr[4][4];                    // [mt][kt]
    int wbpk[4][4];                   // [mt][r]: lo=Kc*W_ih bf16, hi=Kc*bias bf16
#pragma unroll
    for (int mt = 0; mt < 4; ++mt) {
        const float Kc = (mt == 2) ? (-2.0f * L2E) : (-L2E);
        const int row = mt * 128 + 16 * w + lm;
#pragma unroll
        for (int kt = 0; kt < 4; ++kt) {
            const float* src = W_hh + row * 128 + kt * 32 + lq * 8;
            float4 v0 = ((const float4*)src)[0];
            float4 v1 = ((const float4*)src)[1];
            int lo = 0, hi = 0;
            lo = __builtin_amdgcn_cvt_pk_fp8_f32(Kc * v0.x, Kc * v0.y, lo, false);
            lo = __builtin_amdgcn_cvt_pk_fp8_f32(Kc * v0.z, Kc * v0.w, lo, true);
            hi = __builtin_amdgcn_cvt_pk_fp8_f32(Kc * v1.x, Kc * v1.y, hi, false);
            hi = __builtin_amdgcn_cvt_pk_fp8_f32(Kc * v1.z, Kc * v1.w, hi, true);
            i2v t; t[0] = lo; t[1] = hi;
            afr[mt][kt] = __builtin_bit_cast(i64, t);
        }
#pragma unroll
        for (int r = 0; r < 4; ++r) {
            const int rr = mt * 128 + 16 * w + 4 * lq + r;
            wbpk[mt][r] = (int)(unsigned)f2bf(Kc * W_ih[rr]) |
                          ((int)(unsigned)f2bf(Kc * (b_ih[rr] + b_hh[rr])) << 16);
        }
    }

    // ---- stage x: col c = nt*16+n runs window w0+nt of batch base_b+n ----
    {   // 16 steps x 32 cols = 512 = one element per thread
        const int t = j >> 5, c = j & 31;
        const int nt = c >> 4, n = c & 15;
        xst[j] = x[(base_b + n) * TT + (w0 + nt) + t];
    }
    for (int i = j; i < 1024; i += 512)
        ((int*)&Hbuf[0][0])[i] = 0;   // h(0) = 0 (fp8 zeros)

    if (pb == 0 && j < 256) {         // out[:, :16] = x[:, :16]
        const int n = j >> 4, tt = j & 15;
        out[(base_b + n) * TT + tt] = x[(base_b + n) * TT + tt];
    }

    // h-write address: lane owns units u0..u0+3 (consecutive fp8 bytes -> int)
    const int u0    = 16 * w + 4 * lq;
    const int wofhB = (u0 >> 5) * 512 + ((u0 >> 3) & 3) * 128 + lm * 8 + (u0 & 7);

    float cst[2][4] = {};             // [nt][r]
    __syncthreads();

    for (int t = 0; t < 16; ++t) {
        const char* hb = &Hbuf[t & 1][0];
        const float xt0 = xst[t * 32 + lm];
        const float xt1 = xst[t * 32 + 16 + lm];
        f4v cv[4][2];                 // [mt][nt]
#pragma unroll
        for (int mt = 0; mt < 4; ++mt)
#pragma unroll
            for (int r = 0; r < 4; ++r) {
                const int pk = wbpk[mt][r];
                const float wihf  = __builtin_bit_cast(float, pk << 16);
                const float biasf = __builtin_bit_cast(float, pk & 0xffff0000);
                cv[mt][0][r] = fmaf(xt0, wihf, biasf);
                cv[mt][1][r] = fmaf(xt1, wihf, biasf);
            }
#pragma unroll
        for (int kt = 0; kt < 4; ++kt) {
            i64 bfr[2];
#pragma unroll
            for (int nt = 0; nt < 2; ++nt)   // 8B at lane*8 within region
                bfr[nt] = *(const i64*)(hb + nt * 2048 + kt * 512 + l * 8);
#pragma unroll
            for (int nt = 0; nt < 2; ++nt)
#pragma unroll
                for (int mt = 0; mt < 4; ++mt)
                    cv[mt][nt] = __builtin_amdgcn_mfma_f32_16x16x32_fp8_fp8(
                                     afr[mt][kt], bfr[nt], cv[mt][nt], 0, 0, 0);
        }
        char* hw = &Hbuf[(t + 1) & 1][0] + wofhB;
#pragma unroll
        for (int nt = 0; nt < 2; ++nt) {
            float hv4[4];
#pragma unroll
            for (int r = 0; r < 4; ++r) {
                const float ai = sig_e2(cv[0][nt][r]);
                const float af = sig_e2(cv[1][nt][r]);
                const float ag = fmaf(2.0f, sig_e2(cv[2][nt][r]), -1.0f);
                const float ao = sig_e2(cv[3][nt][r]);
                cst[nt][r] = fmaf(af, cst[nt][r], ai * ag);
                const float tc = fmaf(2.0f, sig_e2(-2.0f * L2E * cst[nt][r]), -1.0f);
                hv4[r] = ao * tc;
            }
            int pk8 = 0;
            pk8 = __builtin_amdgcn_cvt_pk_fp8_f32(hv4[0], hv4[1], pk8, false);
            pk8 = __builtin_amdgcn_cvt_pk_fp8_f32(hv4[2], hv4[3], pk8, true);
            *(int*)(hw + nt * 2048) = pk8;
            if (t == 15) {            // bf16 snapshot for the fc epilogue
                i2v p2;
                p2[0] = pk_bf16(hv4[0], hv4[1]);
                p2[1] = pk_bf16(hv4[2], hv4[3]);
                *(i2v*)(&hfin[nt * 2048 + lm * 128 + u0]) = p2;
            }
        }
        __syncthreads();
    }

    // ---- epilogue: col c -> out[base_b+(c&15)][16 + w0 + (c>>4)] ----
    // bf16 h_final in hfin[nt*2048 + n*128 + u]. 8 threads/col, 16 units each.
    if (j < 256) {
        const int c  = j >> 3;        // 0..31
        const int p  = j & 7;         // unit chunk: units p*16 .. p*16+15
        const int nt = c >> 4, n = c & 15;
        const short* hf = &hfin[nt * 2048 + n * 128 + p * 16];
        float acc = 0.f;
#pragma unroll
        for (int h8 = 0; h8 < 2; ++h8) {
            const s8v hv = *(const s8v*)(hf + 8 * h8);
#pragma unroll
            for (int ii = 0; ii < 8; ++ii)
                acc = fmaf(fc_W[p * 16 + 8 * h8 + ii], bf2f(hv[ii]), acc);
        }
        parts[j] = acc;
    }
    __syncthreads();
    if (j < 32) {
        float v = fc_b[0];
#pragma unroll
        for (int k = 0; k < 8; ++k) v += parts[j * 8 + k];
        const int nt = j >> 4, n = j & 15;
        out[(base_b + n) * TT + WIN + w0 + nt] = (v >= 0.f) ? v : 0.3f * v;
    }
}

extern "C" void kernel_launch(void* const* d_in, const int* in_sizes, int n_in,
                              void* d_out, int out_size, void* d_ws, size_t ws_size,
                              hipStream_t stream) {
    const float* x    = (const float*)d_in[0];
    const float* W_ih = (const float*)d_in[1];
    const float* W_hh = (const float*)d_in[2];
    const float* b_ih = (const float*)d_in[3];
    const float* b_hh = (const float*)d_in[4];
    const float* fc_W = (const float*)d_in[5];
    const float* fc_b = (const float*)d_in[6];
    float* out = (float*)d_out;

    lstm_mfma_kernel<<<dim3(120, 8), dim3(512), 0, stream>>>(
        x, W_ih, W_hh, b_ih, b_hh, fc_W, fc_b, out);
}